// Round 3
// baseline (566.276 us; speedup 1.0000x reference)
//
#include <hip/hip_runtime.h>

#define L_SEQ 4096
#define DM    1024
#define NH    16
#define HD    64

typedef unsigned short ushort_t;
typedef __attribute__((ext_vector_type(8))) short bf16x8;
typedef __attribute__((ext_vector_type(4))) float f32x4;

__device__ inline unsigned short f2bf(float f) {
    union { float f; unsigned int u; } v; v.f = f;
    unsigned int r = v.u + 0x7fffu + ((v.u >> 16) & 1u);
    return (unsigned short)(r >> 16);
}

// ---------------------------------------------------------------------------
// Runtime input-dtype detection. Reads x's raw bits as u16. bf16 N(0,1) data
// never has |v| >= 512 (exp >= 0x88); fp32 data's low-mantissa halves are
// ~uniform random bits -> ~47% hit. 64-sample ballot: misdetect p ~ 1e-10.
// Deterministic across blocks/calls (same data every call).
// ---------------------------------------------------------------------------
__device__ inline bool detect_f32(const ushort_t* xraw) {
    __shared__ int s_flag;
    const int t = threadIdx.x;
    if (t < 64) {
        unsigned e = (xraw[2 * t] >> 7) & 0xFFu;   // even u16 = fp32 low halves
        unsigned long long m = __ballot(e >= 0x88u);
        if (t == 0) s_flag = (__popcll(m) >= 8) ? 1 : 0;
    }
    __syncthreads();
    return s_flag != 0;
}

// ---------------------------------------------------------------------------
// Generic GEMM: C[M,N] = A[M,K] * B[K,N], fp32 accum. N = K = 1024 fixed.
// Block tile 64x64, BK=32, 256 threads (4 waves, 2x2). A/B may be fp32 or
// bf16 in global (converted inline during LDS staging); C out fp32 or bf16.
// ---------------------------------------------------------------------------
__device__ inline void gemm_body(const void* __restrict__ Av,
                                 const void* __restrict__ Bv,
                                 void* __restrict__ Cv,
                                 bool a_f32, bool b_f32, bool c_f32) {
    constexpr int N = 1024, K = 1024;
    constexpr int BK = 32, LDA = 40;      // 80B rows: 16B-aligned, 2-way banks (free)
    __shared__ ushort_t As[64][LDA];
    __shared__ ushort_t Bt[64][LDA];

    const int t    = threadIdx.x;
    const int m0   = blockIdx.y * 64, n0 = blockIdx.x * 64;
    const int lane = t & 63, wave = t >> 6;
    const int l15  = lane & 15, quad = lane >> 4;
    const int mw   = (wave >> 1) * 32, nw = (wave & 1) * 32;

    const ushort_t* Ah = (const ushort_t*)Av;
    const float*    Af = (const float*)Av;
    const ushort_t* Bh = (const ushort_t*)Bv;
    const float*    Bf = (const float*)Bv;

    f32x4 acc[2][2] = {};

    const int ar = t >> 2, ac = (t & 3) * 8;   // A stage: 64 rows x 4 chunks
    const int bk = t >> 3, bn = (t & 7) * 8;   // B stage: 32 rows x 8 chunks

    for (int k0 = 0; k0 < K; k0 += BK) {
        if (a_f32) {
            const float* p = Af + (size_t)(m0 + ar) * K + k0 + ac;
            float4 v0 = *(const float4*)p;
            float4 v1 = *(const float4*)(p + 4);
            ushort_t pk[8] = {f2bf(v0.x), f2bf(v0.y), f2bf(v0.z), f2bf(v0.w),
                              f2bf(v1.x), f2bf(v1.y), f2bf(v1.z), f2bf(v1.w)};
            *(uint4*)&As[ar][ac] = *(const uint4*)pk;
        } else {
            *(uint4*)&As[ar][ac] = *(const uint4*)(Ah + (size_t)(m0 + ar) * K + k0 + ac);
        }

        ushort_t bvs[8];
        if (b_f32) {
            const float* p = Bf + (size_t)(k0 + bk) * N + n0 + bn;
            float4 v0 = *(const float4*)p;
            float4 v1 = *(const float4*)(p + 4);
            bvs[0] = f2bf(v0.x); bvs[1] = f2bf(v0.y); bvs[2] = f2bf(v0.z); bvs[3] = f2bf(v0.w);
            bvs[4] = f2bf(v1.x); bvs[5] = f2bf(v1.y); bvs[6] = f2bf(v1.z); bvs[7] = f2bf(v1.w);
        } else {
            *(uint4*)bvs = *(const uint4*)(Bh + (size_t)(k0 + bk) * N + n0 + bn);
        }
        #pragma unroll
        for (int j = 0; j < 8; ++j) Bt[bn + j][bk] = bvs[j];

        __syncthreads();   // orders scalar Bt writes vs vector reads too (TBAA)

        bf16x8 a0 = *(const bf16x8*)(&As[mw +      l15][quad * 8]);
        bf16x8 a1 = *(const bf16x8*)(&As[mw + 16 + l15][quad * 8]);
        bf16x8 b0 = *(const bf16x8*)(&Bt[nw +      l15][quad * 8]);
        bf16x8 b1 = *(const bf16x8*)(&Bt[nw + 16 + l15][quad * 8]);
        acc[0][0] = __builtin_amdgcn_mfma_f32_16x16x32_bf16(a0, b0, acc[0][0], 0, 0, 0);
        acc[0][1] = __builtin_amdgcn_mfma_f32_16x16x32_bf16(a0, b1, acc[0][1], 0, 0, 0);
        acc[1][0] = __builtin_amdgcn_mfma_f32_16x16x32_bf16(a1, b0, acc[1][0], 0, 0, 0);
        acc[1][1] = __builtin_amdgcn_mfma_f32_16x16x32_bf16(a1, b1, acc[1][1], 0, 0, 0);

        __syncthreads();
    }

    ushort_t* Ch = (ushort_t*)Cv;
    float*    Cf = (float*)Cv;
    #pragma unroll
    for (int mi = 0; mi < 2; ++mi)
        #pragma unroll
        for (int ni = 0; ni < 2; ++ni)
            #pragma unroll
            for (int r = 0; r < 4; ++r) {
                int row = m0 + mw + mi * 16 + quad * 4 + r;   // C row = quad*4+reg (verified)
                int col = n0 + nw + ni * 16 + l15;            // C col = lane&15
                float val = acc[mi][ni][r];
                if (c_f32) Cf[(size_t)row * N + col] = val;
                else       Ch[(size_t)row * N + col] = f2bf(val);
            }
}

__global__ __launch_bounds__(256) void qkv_kernel(const void* __restrict__ x,
                                                  const void* __restrict__ wq,
                                                  const void* __restrict__ wk,
                                                  const void* __restrict__ wv,
                                                  ushort_t* Q, ushort_t* K, ushort_t* V) {
    bool f32 = detect_f32((const ushort_t*)x);
    const void* B = (blockIdx.z == 0) ? wq : (blockIdx.z == 1 ? wk : wv);
    void*       C = (blockIdx.z == 0) ? Q  : (blockIdx.z == 1 ? K  : V);
    gemm_body(x, B, C, f32, f32, false);
}

__global__ __launch_bounds__(256) void ogemm_kernel(const void* __restrict__ xdet,
                                                    const ushort_t* __restrict__ A,
                                                    const void* __restrict__ W,
                                                    void* __restrict__ C) {
    bool f32 = detect_f32((const ushort_t*)xdet);
    gemm_body(A, W, C, false, f32, f32);
}

// ---------------------------------------------------------------------------
// Flash attention with ALiBi + causal. Block = 64 queries x 1 head.
// 4 waves, each owns 16 query rows. KV tiles of 64, only t <= qb (causal).
// All inputs are canonical bf16 ws buffers. O may alias Q (per-block regions
// are identical and disjoint across blocks; read-before-write).
// ---------------------------------------------------------------------------
__global__ __launch_bounds__(256) void attn_kernel(const ushort_t* Q,
                                                   const ushort_t* __restrict__ Kp,
                                                   const ushort_t* __restrict__ Vp,
                                                   ushort_t* O) {
    constexpr int LDS = 72;   // 144B rows: 16B-aligned, 2-way banks (free)
    __shared__ ushort_t Qs[64][LDS];
    __shared__ ushort_t Ks[64][LDS];
    __shared__ ushort_t Vs[64][LDS];   // transposed: [dim][kv]
    __shared__ ushort_t Ps[64][LDS];

    const int h  = blockIdx.y;
    const int qb = gridDim.x - 1 - blockIdx.x;   // biggest blocks first (causal imbalance)
    const int q0 = qb * 64;
    const int t  = threadIdx.x;
    const int lane = t & 63, wave = t >> 6;
    const int l15  = lane & 15, quad = lane >> 4;
    const float slope = exp2f(-0.5f * (float)(h + 1));  // 2^(-8/16 * (h+1))

    #pragma unroll
    for (int i = 0; i < 2; ++i) {
        int idx = t + i * 256;
        int r = idx >> 3, c = (idx & 7) * 8;
        *(uint4*)&Qs[r][c] = *(const uint4*)(Q + (size_t)(q0 + r) * DM + h * HD + c);
    }

    f32x4 acc_o[4] = {};
    float m_pr[4], l_r[4];
    int   row_g[4];
    #pragma unroll
    for (int r = 0; r < 4; ++r) {
        m_pr[r] = -1e30f; l_r[r] = 0.f;
        row_g[r] = q0 + wave * 16 + quad * 4 + r;
    }

    for (int tv = 0; tv <= qb; ++tv) {
        const int kv0 = tv * 64;
        __syncthreads();   // previous iter's K/V/P reads done before overwrite
        #pragma unroll
        for (int i = 0; i < 2; ++i) {
            int idx = t + i * 256;
            int r = idx >> 3, c = (idx & 7) * 8;
            *(uint4*)&Ks[r][c] = *(const uint4*)(Kp + (size_t)(kv0 + r) * DM + h * HD + c);
            uint4 vv = *(const uint4*)(Vp + (size_t)(kv0 + r) * DM + h * HD + c);
            const ushort_t* vs = (const ushort_t*)&vv;
            #pragma unroll
            for (int j = 0; j < 8; ++j) Vs[c + j][r] = vs[j];   // transpose scatter
        }
        __syncthreads();

        // S = Q K^T  (rows = queries in C-layout, cols = kv)
        f32x4 sacc[4] = {};
        #pragma unroll
        for (int kt = 0; kt < 2; ++kt) {
            bf16x8 a = *(const bf16x8*)&Qs[wave * 16 + l15][kt * 32 + quad * 8];
            #pragma unroll
            for (int nt = 0; nt < 4; ++nt) {
                bf16x8 b = *(const bf16x8*)&Ks[nt * 16 + l15][kt * 32 + quad * 8];
                sacc[nt] = __builtin_amdgcn_mfma_f32_16x16x32_bf16(a, b, sacc[nt], 0, 0, 0);
            }
        }

        // scores: /sqrt(hd) + alibi, causal mask
        float sv[4][4];
        #pragma unroll
        for (int nt = 0; nt < 4; ++nt) {
            int col = kv0 + nt * 16 + l15;
            #pragma unroll
            for (int r = 0; r < 4; ++r) {
                float s = sacc[nt][r] * 0.125f + slope * (float)(col - row_g[r]);
                sv[nt][r] = (col <= row_g[r]) ? s : -1e30f;
            }
        }

        // online softmax: row max over (4 nt) x (16 lanes of quad)
        float alpha[4];
        #pragma unroll
        for (int r = 0; r < 4; ++r) {
            float mx = fmaxf(fmaxf(sv[0][r], sv[1][r]), fmaxf(sv[2][r], sv[3][r]));
            mx = fmaxf(mx, __shfl_xor(mx, 1));
            mx = fmaxf(mx, __shfl_xor(mx, 2));
            mx = fmaxf(mx, __shfl_xor(mx, 4));
            mx = fmaxf(mx, __shfl_xor(mx, 8));
            float m_new = fmaxf(m_pr[r], mx);
            alpha[r] = __expf(m_pr[r] - m_new);
            m_pr[r]  = m_new;
        }

        #pragma unroll
        for (int nt = 0; nt < 4; ++nt)
            #pragma unroll
            for (int r = 0; r < 4; ++r)
                sv[nt][r] = __expf(sv[nt][r] - m_pr[r]);   // masked -> exp(-huge) = 0

        #pragma unroll
        for (int r = 0; r < 4; ++r) {
            float rs = sv[0][r] + sv[1][r] + sv[2][r] + sv[3][r];
            rs += __shfl_xor(rs, 1);
            rs += __shfl_xor(rs, 2);
            rs += __shfl_xor(rs, 4);
            rs += __shfl_xor(rs, 8);
            l_r[r] = l_r[r] * alpha[r] + rs;
        }

        #pragma unroll
        for (int nt = 0; nt < 4; ++nt)
            #pragma unroll
            for (int r = 0; r < 4; ++r)
                acc_o[nt][r] *= alpha[r];

        // C-layout -> A-layout via LDS
        #pragma unroll
        for (int nt = 0; nt < 4; ++nt)
            #pragma unroll
            for (int r = 0; r < 4; ++r)
                Ps[wave * 16 + quad * 4 + r][nt * 16 + l15] = f2bf(sv[nt][r]);

        __syncthreads();   // orders scalar Ps writes before vector Ps reads

        // O += P * V  (B operand = Vs rows = head-dim)
        #pragma unroll
        for (int kt = 0; kt < 2; ++kt) {
            bf16x8 a = *(const bf16x8*)&Ps[wave * 16 + l15][kt * 32 + quad * 8];
            #pragma unroll
            for (int nt = 0; nt < 4; ++nt) {
                bf16x8 b = *(const bf16x8*)&Vs[nt * 16 + l15][kt * 32 + quad * 8];
                acc_o[nt] = __builtin_amdgcn_mfma_f32_16x16x32_bf16(a, b, acc_o[nt], 0, 0, 0);
            }
        }
    }

    #pragma unroll
    for (int nt = 0; nt < 4; ++nt)
        #pragma unroll
        for (int r = 0; r < 4; ++r) {
            float o = acc_o[nt][r] / l_r[r];
            O[(size_t)row_g[r] * DM + h * HD + nt * 16 + l15] = f2bf(o);
        }
}

// ---------------------------------------------------------------------------
extern "C" void kernel_launch(void* const* d_in, const int* in_sizes, int n_in,
                              void* d_out, int out_size, void* d_ws, size_t ws_size,
                              hipStream_t stream) {
    const void* x  = d_in[0];
    const void* wq = d_in[1];
    const void* wk = d_in[2];
    const void* wv = d_in[3];
    const void* wo = d_in[4];

    const size_t SZ = (size_t)L_SEQ * DM;
    ushort_t* Qp = (ushort_t*)d_ws;
    ushort_t* Kp = Qp + SZ;
    ushort_t* Vp = Kp + SZ;
    ushort_t* An = Qp;        // aliases Q (safe: per-block read-before-write,
                              // identical tile regions) -> ws = 3*8MB = 24MB

    qkv_kernel<<<dim3(DM / 64, L_SEQ / 64, 3), 256, 0, stream>>>(x, wq, wk, wv, Qp, Kp, Vp);
    attn_kernel<<<dim3(L_SEQ / 64, NH), 256, 0, stream>>>(Qp, Kp, Vp, An);
    ogemm_kernel<<<dim3(DM / 64, L_SEQ / 64), 256, 0, stream>>>(x, An, wo, d_out);
}

// Round 4
// 366.112 us; speedup vs baseline: 1.5467x; 1.5467x over previous
//
#include <hip/hip_runtime.h>

#define L_SEQ 4096
#define DM    1024
#define NH    16
#define HD    64

typedef unsigned short ushort_t;
typedef __attribute__((ext_vector_type(8))) short bf16x8;
typedef __attribute__((ext_vector_type(4))) float f32x4;

__device__ inline unsigned short f2bf(float f) {
    union { float f; unsigned int u; } v; v.f = f;
    unsigned int r = v.u + 0x7fffu + ((v.u >> 16) & 1u);
    return (unsigned short)(r >> 16);
}

// ---------------------------------------------------------------------------
// Runtime input-dtype detection (bf16 vs fp32 global buffers). Verified R3.
// ---------------------------------------------------------------------------
__device__ inline bool detect_f32(const ushort_t* xraw) {
    __shared__ int s_flag;
    const int t = threadIdx.x;
    if (t < 64) {
        unsigned e = (xraw[2 * t] >> 7) & 0xFFu;
        unsigned long long m = __ballot(e >= 0x88u);
        if (t == 0) s_flag = (__popcll(m) >= 8) ? 1 : 0;
    }
    __syncthreads();
    return s_flag != 0;
}

// ---------------------------------------------------------------------------
// Generic GEMM (R3, passing): C[M,N] = A[M,K]*B[K,N], 64x64 tile, BK=32.
// ---------------------------------------------------------------------------
__device__ inline void gemm_body(const void* __restrict__ Av,
                                 const void* __restrict__ Bv,
                                 void* __restrict__ Cv,
                                 bool a_f32, bool b_f32, bool c_f32) {
    constexpr int N = 1024, K = 1024;
    constexpr int BK = 32, LDA = 40;
    __shared__ ushort_t As[64][LDA];
    __shared__ ushort_t Bt[64][LDA];

    const int t    = threadIdx.x;
    const int m0   = blockIdx.y * 64, n0 = blockIdx.x * 64;
    const int lane = t & 63, wave = t >> 6;
    const int l15  = lane & 15, quad = lane >> 4;
    const int mw   = (wave >> 1) * 32, nw = (wave & 1) * 32;

    const ushort_t* Ah = (const ushort_t*)Av;
    const float*    Af = (const float*)Av;
    const ushort_t* Bh = (const ushort_t*)Bv;
    const float*    Bf = (const float*)Bv;

    f32x4 acc[2][2] = {};

    const int ar = t >> 2, ac = (t & 3) * 8;
    const int bk = t >> 3, bn = (t & 7) * 8;

    for (int k0 = 0; k0 < K; k0 += BK) {
        if (a_f32) {
            const float* p = Af + (size_t)(m0 + ar) * K + k0 + ac;
            float4 v0 = *(const float4*)p;
            float4 v1 = *(const float4*)(p + 4);
            ushort_t pk[8] = {f2bf(v0.x), f2bf(v0.y), f2bf(v0.z), f2bf(v0.w),
                              f2bf(v1.x), f2bf(v1.y), f2bf(v1.z), f2bf(v1.w)};
            *(uint4*)&As[ar][ac] = *(const uint4*)pk;
        } else {
            *(uint4*)&As[ar][ac] = *(const uint4*)(Ah + (size_t)(m0 + ar) * K + k0 + ac);
        }

        ushort_t bvs[8];
        if (b_f32) {
            const float* p = Bf + (size_t)(k0 + bk) * N + n0 + bn;
            float4 v0 = *(const float4*)p;
            float4 v1 = *(const float4*)(p + 4);
            bvs[0] = f2bf(v0.x); bvs[1] = f2bf(v0.y); bvs[2] = f2bf(v0.z); bvs[3] = f2bf(v0.w);
            bvs[4] = f2bf(v1.x); bvs[5] = f2bf(v1.y); bvs[6] = f2bf(v1.z); bvs[7] = f2bf(v1.w);
        } else {
            *(uint4*)bvs = *(const uint4*)(Bh + (size_t)(k0 + bk) * N + n0 + bn);
        }
        #pragma unroll
        for (int j = 0; j < 8; ++j) Bt[bn + j][bk] = bvs[j];

        __syncthreads();

        bf16x8 a0 = *(const bf16x8*)(&As[mw +      l15][quad * 8]);
        bf16x8 a1 = *(const bf16x8*)(&As[mw + 16 + l15][quad * 8]);
        bf16x8 b0 = *(const bf16x8*)(&Bt[nw +      l15][quad * 8]);
        bf16x8 b1 = *(const bf16x8*)(&Bt[nw + 16 + l15][quad * 8]);
        acc[0][0] = __builtin_amdgcn_mfma_f32_16x16x32_bf16(a0, b0, acc[0][0], 0, 0, 0);
        acc[0][1] = __builtin_amdgcn_mfma_f32_16x16x32_bf16(a0, b1, acc[0][1], 0, 0, 0);
        acc[1][0] = __builtin_amdgcn_mfma_f32_16x16x32_bf16(a1, b0, acc[1][0], 0, 0, 0);
        acc[1][1] = __builtin_amdgcn_mfma_f32_16x16x32_bf16(a1, b1, acc[1][1], 0, 0, 0);

        __syncthreads();
    }

    ushort_t* Ch = (ushort_t*)Cv;
    float*    Cf = (float*)Cv;
    #pragma unroll
    for (int mi = 0; mi < 2; ++mi)
        #pragma unroll
        for (int ni = 0; ni < 2; ++ni)
            #pragma unroll
            for (int r = 0; r < 4; ++r) {
                int row = m0 + mw + mi * 16 + quad * 4 + r;
                int col = n0 + nw + ni * 16 + l15;
                float val = acc[mi][ni][r];
                if (c_f32) Cf[(size_t)row * N + col] = val;
                else       Ch[(size_t)row * N + col] = f2bf(val);
            }
}

__global__ __launch_bounds__(256) void qkv_kernel(const void* __restrict__ x,
                                                  const void* __restrict__ wq,
                                                  const void* __restrict__ wk,
                                                  const void* __restrict__ wv,
                                                  ushort_t* Q, ushort_t* K, ushort_t* V) {
    bool f32 = detect_f32((const ushort_t*)x);
    const void* B = (blockIdx.z == 0) ? wq : (blockIdx.z == 1 ? wk : wv);
    void*       C = (blockIdx.z == 0) ? Q  : (blockIdx.z == 1 ? K  : V);
    gemm_body(x, B, C, f32, f32, false);
}

__global__ __launch_bounds__(256) void ogemm_kernel(const void* __restrict__ xdet,
                                                    const ushort_t* __restrict__ A,
                                                    const void* __restrict__ W,
                                                    void* __restrict__ C) {
    bool f32 = detect_f32((const ushort_t*)xdet);
    gemm_body(A, W, C, false, f32, f32);
}

// ---------------------------------------------------------------------------
// V transpose: Vp[L][DM] -> Vt[DM][L] (coalesced b16 via padded LDS tile)
// ---------------------------------------------------------------------------
__global__ __launch_bounds__(256) void transpose_kernel(const ushort_t* __restrict__ Vp,
                                                        ushort_t* __restrict__ Vt) {
    __shared__ ushort_t T[64][65];
    const int l0 = blockIdx.x * 64, d0 = blockIdx.y * 64;
    const int t  = threadIdx.x;
    #pragma unroll
    for (int i = 0; i < 16; ++i) {
        int e = t + i * 256;
        int r = e >> 6, c = e & 63;
        T[r][c] = Vp[(size_t)(l0 + r) * DM + d0 + c];
    }
    __syncthreads();
    #pragma unroll
    for (int i = 0; i < 16; ++i) {
        int e = t + i * 256;
        int d = e >> 6, l = e & 63;
        Vt[(size_t)(d0 + d) * L_SEQ + l0 + l] = T[l][d];
    }
}

// ---------------------------------------------------------------------------
// Flash attention, S^T formulation. Block = 2 complementary q-tiles (63-bx,
// bx) x 1 head = uniform 33 KV-stages of 128. 4 waves x 16 queries.
// S^T = K·Q^T: lane holds 32 kv-scores for ONE query (q=l15) -> in-register
// softmax reductions + 2 shuffles. P^T packed to Pt[q][kv] with b64 writes
// (exact PV A-operand layout). V pre-transposed in global -> all staging
// vectorized, conflict-free. Base-2 softmax (slope,1/sqrt(d) folded).
// ---------------------------------------------------------------------------
__global__ __launch_bounds__(256) void attn_kernel(const ushort_t* __restrict__ Q,
                                                   const ushort_t* __restrict__ Kp,
                                                   const ushort_t* __restrict__ Vt,
                                                   ushort_t* __restrict__ O) {
    __shared__ ushort_t Ks[128][72];    // [kv][d]   18.0 KB
    __shared__ ushort_t Vs[64][136];    // [d][kv]   17.0 KB
    __shared__ ushort_t Pt[64][136];    // [q][kv]   17.0 KB  (wave-private rows)

    const int h    = blockIdx.y;
    const int bx   = blockIdx.x;               // 0..31
    const int t    = threadIdx.x;
    const int lane = t & 63, wave = t >> 6;
    const int l15  = lane & 15, quad = lane >> 4;
    const float LOG2E  = 1.44269504f;
    const float slope2 = exp2f(-0.5f * (float)(h + 1)) * LOG2E;  // slope*log2e
    const float c0     = 0.125f * LOG2E;                          // 1/sqrt(64)*log2e
    const float qd4f   = (float)(quad * 4);

    #pragma unroll
    for (int half = 0; half < 2; ++half) {
        const int qb = half ? bx : (63 - bx);
        const int q0 = qb * 64;
        const int qg = q0 + wave * 16 + l15;   // this lane's query row
        const float qf = (float)qg;

        // Q fragments, register-resident for all stages (B-operand of S^T)
        bf16x8 bq[2];
        #pragma unroll
        for (int kt = 0; kt < 2; ++kt)
            bq[kt] = *(const bf16x8*)(Q + (size_t)qg * DM + h * HD + kt * 32 + quad * 8);

        f32x4 acc_o[4] = {};
        float m2 = -1e30f, l_r = 0.f;

        const int nst = (qb + 2) >> 1;         // ceil((qb+1)/2) 128-stages
        for (int s = 0; s < nst; ++s) {
            const int kv0 = s * 128;
            __syncthreads();   // prior-stage Ks/Vs/Pt reads complete
            #pragma unroll
            for (int i = 0; i < 4; ++i) {      // K: 128 kv x 64 d
                int idx = t + i * 256;
                int r = idx >> 3, c = (idx & 7) * 8;
                *(uint4*)&Ks[r][c] = *(const uint4*)(Kp + (size_t)(kv0 + r) * DM + h * HD + c);
            }
            #pragma unroll
            for (int i = 0; i < 4; ++i) {      // V^T: 64 d x 128 kv
                int idx = t + i * 256;
                int d = idx >> 4, c = (idx & 15) * 8;
                *(uint4*)&Vs[d][c] = *(const uint4*)(Vt + (size_t)(h * HD + d) * L_SEQ + kv0 + c);
            }
            __syncthreads();

            // S^T[kv][q]: A = K (m=kv), B = Q (n=q). Lane: q=l15, kv=mt*16+quad*4+r
            f32x4 sacc[8];
            #pragma unroll
            for (int mt = 0; mt < 8; ++mt) sacc[mt] = (f32x4){0.f, 0.f, 0.f, 0.f};
            #pragma unroll
            for (int kt = 0; kt < 2; ++kt)
                #pragma unroll
                for (int mt = 0; mt < 8; ++mt) {
                    bf16x8 a = *(const bf16x8*)&Ks[mt * 16 + l15][kt * 32 + quad * 8];
                    sacc[mt] = __builtin_amdgcn_mfma_f32_16x16x32_bf16(a, bq[kt], sacc[mt], 0, 0, 0);
                }

            // scores in log2 domain: s2 = qk*c0 + slope2*(kv - q)
            const bool diag = (kv0 + 128 > q0);     // block-uniform
            const float off = slope2 * ((float)kv0 - qf);
            #pragma unroll
            for (int mt = 0; mt < 8; ++mt)
                #pragma unroll
                for (int r = 0; r < 4; ++r) {
                    float kvl = qd4f + (float)(mt * 16 + r);
                    float s2  = fmaf(sacc[mt][r], c0, fmaf(slope2, kvl, off));
                    if (diag) {
                        int kvg = kv0 + mt * 16 + quad * 4 + r;
                        s2 = (kvg <= qg) ? s2 : -1e30f;
                    }
                    sacc[mt][r] = s2;
                }

            // row max: in-register + quad-combine (lanes ^16,^32 share q=l15)
            float mx = sacc[0][0];
            #pragma unroll
            for (int mt = 0; mt < 8; ++mt)
                #pragma unroll
                for (int r = 0; r < 4; ++r) mx = fmaxf(mx, sacc[mt][r]);
            mx = fmaxf(mx, __shfl_xor(mx, 16));
            mx = fmaxf(mx, __shfl_xor(mx, 32));
            float m_new = fmaxf(m2, mx);
            float alpha = exp2f(m2 - m_new);
            m2 = m_new;

            // exp2 + row sum
            float rs = 0.f;
            #pragma unroll
            for (int mt = 0; mt < 8; ++mt)
                #pragma unroll
                for (int r = 0; r < 4; ++r) {
                    float p = exp2f(sacc[mt][r] - m2);
                    sacc[mt][r] = p;
                    rs += p;
                }
            rs += __shfl_xor(rs, 16);
            rs += __shfl_xor(rs, 32);
            l_r = l_r * alpha + rs;

            // rescale O rows (row q_local = quad*4+r needs alpha of that query)
            float alpha_row[4];
            #pragma unroll
            for (int r = 0; r < 4; ++r) alpha_row[r] = __shfl(alpha, quad * 4 + r);
            #pragma unroll
            for (int nt = 0; nt < 4; ++nt)
                #pragma unroll
                for (int r = 0; r < 4; ++r) acc_o[nt][r] *= alpha_row[r];

            // pack P^T -> Pt[q][kv]: 4 consecutive kv per lane, b64 writes.
            // v_perm truncation pack: (hi & 0xffff0000) | (lo >> 16)
            #pragma unroll
            for (int mt = 0; mt < 8; ++mt) {
                union { float f; unsigned u; } a0, a1, a2, a3;
                a0.f = sacc[mt][0]; a1.f = sacc[mt][1];
                a2.f = sacc[mt][2]; a3.f = sacc[mt][3];
                uint2 w;
                w.x = __builtin_amdgcn_perm(a1.u, a0.u, 0x07060302);
                w.y = __builtin_amdgcn_perm(a3.u, a2.u, 0x07060302);
                *(uint2*)&Pt[wave * 16 + l15][mt * 16 + quad * 4] = w;
            }
            __threadfence_block();   // order wave-local Pt writes before reads

            // O += P·V: A = Pt[q][kv], B = Vs[d][kv]
            #pragma unroll
            for (int kt = 0; kt < 4; ++kt) {
                bf16x8 a = *(const bf16x8*)&Pt[wave * 16 + l15][kt * 32 + quad * 8];
                #pragma unroll
                for (int nt = 0; nt < 4; ++nt) {
                    bf16x8 b = *(const bf16x8*)&Vs[nt * 16 + l15][kt * 32 + quad * 8];
                    acc_o[nt] = __builtin_amdgcn_mfma_f32_16x16x32_bf16(a, b, acc_o[nt], 0, 0, 0);
                }
            }
        }

        // epilogue: O row q_local = quad*4+r, col d = nt*16+l15
        float linv[4];
        #pragma unroll
        for (int r = 0; r < 4; ++r) linv[r] = 1.0f / __shfl(l_r, quad * 4 + r);
        #pragma unroll
        for (int nt = 0; nt < 4; ++nt)
            #pragma unroll
            for (int r = 0; r < 4; ++r) {
                int row = q0 + wave * 16 + quad * 4 + r;
                O[(size_t)row * DM + h * HD + nt * 16 + l15] = f2bf(acc_o[nt][r] * linv[r]);
            }
    }
}

// ---------------------------------------------------------------------------
extern "C" void kernel_launch(void* const* d_in, const int* in_sizes, int n_in,
                              void* d_out, int out_size, void* d_ws, size_t ws_size,
                              hipStream_t stream) {
    const void* x  = d_in[0];
    const void* wq = d_in[1];
    const void* wk = d_in[2];
    const void* wv = d_in[3];
    const void* wo = d_in[4];

    const size_t SZ = (size_t)L_SEQ * DM;
    ushort_t* Qp = (ushort_t*)d_ws;
    ushort_t* Kp = Qp + SZ;
    ushort_t* Vp = Kp + SZ;
    ushort_t* Vt = Vp + SZ;   // 4 x 8 MB = 32 MB ws
    ushort_t* An = Vp;        // attn reads Vt (not Vp) -> safe alias

    qkv_kernel<<<dim3(DM / 64, L_SEQ / 64, 3), 256, 0, stream>>>(x, wq, wk, wv, Qp, Kp, Vp);
    transpose_kernel<<<dim3(L_SEQ / 64, DM / 64), 256, 0, stream>>>(Vp, Vt);
    attn_kernel<<<dim3(32, NH), 256, 0, stream>>>(Qp, Kp, Vt, An);
    ogemm_kernel<<<dim3(DM / 64, L_SEQ / 64), 256, 0, stream>>>(x, An, wo, d_out);
}

// Round 5
// 304.541 us; speedup vs baseline: 1.8594x; 1.2022x over previous
//
#include <hip/hip_runtime.h>

#define L_SEQ 4096
#define DM    1024
#define NH    16
#define HD    64

typedef unsigned short ushort_t;
typedef __attribute__((ext_vector_type(8))) short bf16x8;
typedef __attribute__((ext_vector_type(4))) float f32x4;

__device__ inline unsigned short f2bf(float f) {
    union { float f; unsigned int u; } v; v.f = f;
    unsigned int r = v.u + 0x7fffu + ((v.u >> 16) & 1u);
    return (unsigned short)(r >> 16);
}

// async global->LDS, 16B/lane. LDS dest = wave-uniform base + lane*16.
__device__ inline void load_lds16(const ushort_t* g, ushort_t* l) {
    __builtin_amdgcn_global_load_lds(
        (const __attribute__((address_space(1))) unsigned int*)g,
        (__attribute__((address_space(3))) unsigned int*)l, 16, 0, 0);
}

// ---------------------------------------------------------------------------
// Runtime input-dtype detection (bf16 vs fp32 global buffers). Verified R3.
// ---------------------------------------------------------------------------
__device__ inline bool detect_f32(const ushort_t* xraw) {
    __shared__ int s_flag;
    const int t = threadIdx.x;
    if (t < 64) {
        unsigned e = (xraw[2 * t] >> 7) & 0xFFu;
        unsigned long long m = __ballot(e >= 0x88u);
        if (t == 0) s_flag = (__popcll(m) >= 8) ? 1 : 0;
    }
    __syncthreads();
    return s_flag != 0;
}

// ---------------------------------------------------------------------------
// x -> bf16 canonical buffer (4M elems, 8 elems/thread)
// ---------------------------------------------------------------------------
__global__ __launch_bounds__(256) void convert_x(const void* __restrict__ xv,
                                                 ushort_t* __restrict__ xb) {
    bool f32 = detect_f32((const ushort_t*)xv);
    const int i = (blockIdx.x * 256 + threadIdx.x) * 8;
    if (f32) {
        const float* xf = (const float*)xv;
        float4 v0 = *(const float4*)(xf + i);
        float4 v1 = *(const float4*)(xf + i + 4);
        ushort_t pk[8] = {f2bf(v0.x), f2bf(v0.y), f2bf(v0.z), f2bf(v0.w),
                          f2bf(v1.x), f2bf(v1.y), f2bf(v1.z), f2bf(v1.w)};
        *(uint4*)(xb + i) = *(const uint4*)pk;
    } else {
        *(uint4*)(xb + i) = *(const uint4*)((const ushort_t*)xv + i);
    }
}

// ---------------------------------------------------------------------------
// weights -> bf16 TRANSPOSED wT[n][k] (z picks which of 4 weights)
// ---------------------------------------------------------------------------
__global__ __launch_bounds__(256) void convert_wt(const void* __restrict__ xdet,
                                                  const void* __restrict__ w0,
                                                  const void* __restrict__ w1,
                                                  const void* __restrict__ w2,
                                                  const void* __restrict__ w3,
                                                  ushort_t* __restrict__ wT) {
    bool f32 = detect_f32((const ushort_t*)xdet);
    const int z = blockIdx.z;
    const void* w = (z == 0) ? w0 : (z == 1) ? w1 : (z == 2) ? w2 : w3;
    ushort_t* out = wT + (size_t)z * (DM * DM);
    __shared__ ushort_t T[64][65];
    const int k0 = blockIdx.x * 64, n0 = blockIdx.y * 64;
    const int t = threadIdx.x;
    #pragma unroll
    for (int i = 0; i < 16; ++i) {
        int e = t + i * 256;
        int r = e >> 6, c = e & 63;
        T[r][c] = f32 ? f2bf(((const float*)w)[(size_t)(k0 + r) * DM + n0 + c])
                      : ((const ushort_t*)w)[(size_t)(k0 + r) * DM + n0 + c];
    }
    __syncthreads();
    #pragma unroll
    for (int i = 0; i < 16; ++i) {
        int e = t + i * 256;
        int d = e >> 6, l = e & 63;
        out[(size_t)(n0 + d) * DM + k0 + l] = T[l][d];
    }
}

// ---------------------------------------------------------------------------
// m97-structure GEMM: C[M,1024] = A[M,1024] * Bt[1024,1024]^T (Bt is [n][k]).
// 128x128 tile, BK=32, 256 thr. Both operands staged via global_load_lds x16.
// Per wave-iter: 4 glds + 8 ds_read_b128 + 16 MFMA (the measured 874TF mix).
// ---------------------------------------------------------------------------
__device__ inline void gemm128_body(const ushort_t* __restrict__ A,
                                    const ushort_t* __restrict__ Bt,
                                    void* __restrict__ Cv, bool c_f32) {
    constexpr int K = 1024, NOUT = 1024;
    __shared__ ushort_t As[128 * 32];   // [r][k] rows of 32, unpadded (glds)
    __shared__ ushort_t Bs[128 * 32];

    const int t = threadIdx.x, lane = t & 63, wave = t >> 6;
    const int l15 = lane & 15, quad = lane >> 4;
    const int m0 = blockIdx.y * 128, n0 = blockIdx.x * 128;
    const int mw = (wave >> 1) * 64, nw = (wave & 1) * 64;
    const int srow = lane >> 2, scol = (lane & 3) * 8;   // lane's 16B in a 16-row slab

    f32x4 acc[4][4] = {};

    for (int k0 = 0; k0 < K; k0 += 32) {
        #pragma unroll
        for (int j = 0; j < 2; ++j) {
            const int r0 = wave * 32 + j * 16;   // wave-uniform slab base
            load_lds16(A  + (size_t)(m0 + r0 + srow) * K + k0 + scol, &As[r0 * 32]);
            load_lds16(Bt + (size_t)(n0 + r0 + srow) * K + k0 + scol, &Bs[r0 * 32]);
        }
        __syncthreads();   // drains vmcnt (glds) before fragment reads

        bf16x8 af[4], bf[4];
        #pragma unroll
        for (int i = 0; i < 4; ++i) {
            af[i] = *(const bf16x8*)&As[(mw + i * 16 + l15) * 32 + quad * 8];
            bf[i] = *(const bf16x8*)&Bs[(nw + i * 16 + l15) * 32 + quad * 8];
        }
        #pragma unroll
        for (int mt = 0; mt < 4; ++mt)
            #pragma unroll
            for (int nt = 0; nt < 4; ++nt)
                acc[mt][nt] = __builtin_amdgcn_mfma_f32_16x16x32_bf16(af[mt], bf[nt], acc[mt][nt], 0, 0, 0);

        __syncthreads();
    }

    ushort_t* Ch = (ushort_t*)Cv;
    float*    Cf = (float*)Cv;
    #pragma unroll
    for (int mt = 0; mt < 4; ++mt)
        #pragma unroll
        for (int nt = 0; nt < 4; ++nt)
            #pragma unroll
            for (int r = 0; r < 4; ++r) {
                int row = m0 + mw + mt * 16 + quad * 4 + r;   // C row = quad*4+reg
                int col = n0 + nw + nt * 16 + l15;            // C col = lane&15
                if (c_f32) Cf[(size_t)row * NOUT + col] = acc[mt][nt][r];
                else       Ch[(size_t)row * NOUT + col] = f2bf(acc[mt][nt][r]);
            }
}

__global__ __launch_bounds__(256) void qkv128(const ushort_t* __restrict__ xb,
                                              const ushort_t* __restrict__ wT,
                                              ushort_t* Qp, ushort_t* Kp, ushort_t* Vp) {
    const int z = blockIdx.z;
    const ushort_t* Bt = wT + (size_t)z * (DM * DM);
    ushort_t* C = (z == 0) ? Qp : (z == 1) ? Kp : Vp;
    gemm128_body(xb, Bt, C, false);
}

__global__ __launch_bounds__(256) void ogemm128(const void* __restrict__ xdet,
                                                const ushort_t* __restrict__ An,
                                                const ushort_t* __restrict__ woT,
                                                void* __restrict__ C) {
    bool f32 = detect_f32((const ushort_t*)xdet);
    gemm128_body(An, woT, C, f32);
}

// ---------------------------------------------------------------------------
// V transpose: Vp[L][DM] -> Vt[DM][L]
// ---------------------------------------------------------------------------
__global__ __launch_bounds__(256) void transpose_kernel(const ushort_t* __restrict__ Vp,
                                                        ushort_t* __restrict__ Vt) {
    __shared__ ushort_t T[64][65];
    const int l0 = blockIdx.x * 64, d0 = blockIdx.y * 64;
    const int t  = threadIdx.x;
    #pragma unroll
    for (int i = 0; i < 16; ++i) {
        int e = t + i * 256;
        int r = e >> 6, c = e & 63;
        T[r][c] = Vp[(size_t)(l0 + r) * DM + d0 + c];
    }
    __syncthreads();
    #pragma unroll
    for (int i = 0; i < 16; ++i) {
        int e = t + i * 256;
        int d = e >> 6, l = e & 63;
        Vt[(size_t)(d0 + d) * L_SEQ + l0 + l] = T[l][d];
    }
}

// ---------------------------------------------------------------------------
// Flash attention, S^T formulation (R4, verified). Block = 2 complementary
// q-tiles x 1 head, 33 uniform KV-stages of 128.
// ---------------------------------------------------------------------------
__global__ __launch_bounds__(256) void attn_kernel(const ushort_t* __restrict__ Q,
                                                   const ushort_t* __restrict__ Kp,
                                                   const ushort_t* __restrict__ Vt,
                                                   ushort_t* __restrict__ O) {
    __shared__ ushort_t Ks[128][72];
    __shared__ ushort_t Vs[64][136];
    __shared__ ushort_t Pt[64][136];

    const int h    = blockIdx.y;
    const int bx   = blockIdx.x;
    const int t    = threadIdx.x;
    const int lane = t & 63, wave = t >> 6;
    const int l15  = lane & 15, quad = lane >> 4;
    const float LOG2E  = 1.44269504f;
    const float slope2 = exp2f(-0.5f * (float)(h + 1)) * LOG2E;
    const float c0     = 0.125f * LOG2E;
    const float qd4f   = (float)(quad * 4);

    #pragma unroll
    for (int half = 0; half < 2; ++half) {
        const int qb = half ? bx : (63 - bx);
        const int q0 = qb * 64;
        const int qg = q0 + wave * 16 + l15;
        const float qf = (float)qg;

        bf16x8 bq[2];
        #pragma unroll
        for (int kt = 0; kt < 2; ++kt)
            bq[kt] = *(const bf16x8*)(Q + (size_t)qg * DM + h * HD + kt * 32 + quad * 8);

        f32x4 acc_o[4] = {};
        float m2 = -1e30f, l_r = 0.f;

        const int nst = (qb + 2) >> 1;
        for (int s = 0; s < nst; ++s) {
            const int kv0 = s * 128;
            __syncthreads();
            #pragma unroll
            for (int i = 0; i < 4; ++i) {
                int idx = t + i * 256;
                int r = idx >> 3, c = (idx & 7) * 8;
                *(uint4*)&Ks[r][c] = *(const uint4*)(Kp + (size_t)(kv0 + r) * DM + h * HD + c);
            }
            #pragma unroll
            for (int i = 0; i < 4; ++i) {
                int idx = t + i * 256;
                int d = idx >> 4, c = (idx & 15) * 8;
                *(uint4*)&Vs[d][c] = *(const uint4*)(Vt + (size_t)(h * HD + d) * L_SEQ + kv0 + c);
            }
            __syncthreads();

            f32x4 sacc[8];
            #pragma unroll
            for (int mt = 0; mt < 8; ++mt) sacc[mt] = (f32x4){0.f, 0.f, 0.f, 0.f};
            #pragma unroll
            for (int kt = 0; kt < 2; ++kt)
                #pragma unroll
                for (int mt = 0; mt < 8; ++mt) {
                    bf16x8 a = *(const bf16x8*)&Ks[mt * 16 + l15][kt * 32 + quad * 8];
                    sacc[mt] = __builtin_amdgcn_mfma_f32_16x16x32_bf16(a, bq[kt], sacc[mt], 0, 0, 0);
                }

            const bool diag = (kv0 + 128 > q0);
            const float off = slope2 * ((float)kv0 - qf);
            #pragma unroll
            for (int mt = 0; mt < 8; ++mt)
                #pragma unroll
                for (int r = 0; r < 4; ++r) {
                    float kvl = qd4f + (float)(mt * 16 + r);
                    float s2  = fmaf(sacc[mt][r], c0, fmaf(slope2, kvl, off));
                    if (diag) {
                        int kvg = kv0 + mt * 16 + quad * 4 + r;
                        s2 = (kvg <= qg) ? s2 : -1e30f;
                    }
                    sacc[mt][r] = s2;
                }

            float mx = sacc[0][0];
            #pragma unroll
            for (int mt = 0; mt < 8; ++mt)
                #pragma unroll
                for (int r = 0; r < 4; ++r) mx = fmaxf(mx, sacc[mt][r]);
            mx = fmaxf(mx, __shfl_xor(mx, 16));
            mx = fmaxf(mx, __shfl_xor(mx, 32));
            float m_new = fmaxf(m2, mx);
            float alpha = exp2f(m2 - m_new);
            m2 = m_new;

            float rs = 0.f;
            #pragma unroll
            for (int mt = 0; mt < 8; ++mt)
                #pragma unroll
                for (int r = 0; r < 4; ++r) {
                    float p = exp2f(sacc[mt][r] - m2);
                    sacc[mt][r] = p;
                    rs += p;
                }
            rs += __shfl_xor(rs, 16);
            rs += __shfl_xor(rs, 32);
            l_r = l_r * alpha + rs;

            float alpha_row[4];
            #pragma unroll
            for (int r = 0; r < 4; ++r) alpha_row[r] = __shfl(alpha, quad * 4 + r);
            #pragma unroll
            for (int nt = 0; nt < 4; ++nt)
                #pragma unroll
                for (int r = 0; r < 4; ++r) acc_o[nt][r] *= alpha_row[r];

            #pragma unroll
            for (int mt = 0; mt < 8; ++mt) {
                union { float f; unsigned u; } a0, a1, a2, a3;
                a0.f = sacc[mt][0]; a1.f = sacc[mt][1];
                a2.f = sacc[mt][2]; a3.f = sacc[mt][3];
                uint2 w;
                w.x = __builtin_amdgcn_perm(a1.u, a0.u, 0x07060302);
                w.y = __builtin_amdgcn_perm(a3.u, a2.u, 0x07060302);
                *(uint2*)&Pt[wave * 16 + l15][mt * 16 + quad * 4] = w;
            }
            __threadfence_block();

            #pragma unroll
            for (int kt = 0; kt < 4; ++kt) {
                bf16x8 a = *(const bf16x8*)&Pt[wave * 16 + l15][kt * 32 + quad * 8];
                #pragma unroll
                for (int nt = 0; nt < 4; ++nt) {
                    bf16x8 b = *(const bf16x8*)&Vs[nt * 16 + l15][kt * 32 + quad * 8];
                    acc_o[nt] = __builtin_amdgcn_mfma_f32_16x16x32_bf16(a, b, acc_o[nt], 0, 0, 0);
                }
            }
        }

        float linv[4];
        #pragma unroll
        for (int r = 0; r < 4; ++r) linv[r] = 1.0f / __shfl(l_r, quad * 4 + r);
        #pragma unroll
        for (int nt = 0; nt < 4; ++nt)
            #pragma unroll
            for (int r = 0; r < 4; ++r) {
                int row = q0 + wave * 16 + quad * 4 + r;
                O[(size_t)row * DM + h * HD + nt * 16 + l15] = f2bf(acc_o[nt][r] * linv[r]);
            }
    }
}

// ---------------------------------------------------------------------------
extern "C" void kernel_launch(void* const* d_in, const int* in_sizes, int n_in,
                              void* d_out, int out_size, void* d_ws, size_t ws_size,
                              hipStream_t stream) {
    const void* x  = d_in[0];
    const void* wq = d_in[1];
    const void* wk = d_in[2];
    const void* wv = d_in[3];
    const void* wo = d_in[4];

    const size_t SZ = (size_t)L_SEQ * DM;   // 4M elems
    const size_t WZ = (size_t)DM * DM;      // 1M elems
    ushort_t* xb = (ushort_t*)d_ws;         // 8 MB
    ushort_t* wT = xb + SZ;                 // 4 x 2 MB (q,k,v,o transposed bf16)
    ushort_t* Qp = wT + 4 * WZ;             // 8 MB
    ushort_t* Kp = Qp + SZ;                 // 8 MB
    ushort_t* Vp = Kp + SZ;                 // 8 MB
    ushort_t* Vt = Vp + SZ;                 // 8 MB  -> total 48 MB
    ushort_t* An = xb;                      // xb dead after qkv -> safe alias

    convert_x<<<2048, 256, 0, stream>>>(x, xb);
    convert_wt<<<dim3(16, 16, 4), 256, 0, stream>>>(x, wq, wk, wv, wo, wT);
    qkv128<<<dim3(DM / 128, L_SEQ / 128, 3), 256, 0, stream>>>(xb, wT, Qp, Kp, Vp);
    transpose_kernel<<<dim3(L_SEQ / 64, DM / 64), 256, 0, stream>>>(Vp, Vt);
    attn_kernel<<<dim3(32, NH), 256, 0, stream>>>(Qp, Kp, Vt, An);
    ogemm128<<<dim3(DM / 128, L_SEQ / 128), 256, 0, stream>>>(x, An, wT + 3 * WZ, d_out);
}